// Round 10
// baseline (98.157 us; speedup 1.0000x reference)
//
#include <hip/hip_runtime.h>
#include <hip/hip_bf16.h>
#include <math.h>

#define D_SINGLE 512
#define D_PAIR   128
#define RANK     32
#define NROW     512
#define EPS      1e-5f

typedef __attribute__((ext_vector_type(8))) short bf16x8;  // 8 bf16 = 4 VGPRs
typedef __attribute__((ext_vector_type(4))) float f32x4;

__device__ __forceinline__ float dot4(f32x4 a, f32x4 b) {
    return a.x * b.x + a.y * b.y + a.z * b.z + a.w * b.w;
}

// ---------------------------------------------------------------------------
// Fused k1+k2, geometry-preserving (r9 lesson: many small blocks, no fat
// serial blocks). One dispatch, block-specialized:
//  blocks 0..511    : a-side, 256 thr — verbatim r8 k1 math for a-rows only.
//  blocks 512..1535 : b-side, 256 thr. bb = bid-512, g = bb>>4 (j-group),
//                     seg = bb&15 (pr sixteenth).
//    B1: wave w LNs rows g*8+w and g*8+w+4 -> xnb[8][512] LDS (16 KB).
//    B2: thread t -> (jj = t>>5, r = t&31): full dot-512 proj from LDS
//        -> bl[jj*32+r] (+bias).
//    B3: thread t -> pr = seg*256+t: wb[g*8+jj][pr] for jj = 0..7
//        (w_out row slice 128 B/thread, 8 bf16 coalesced stores).
//    B1/B2 recomputed by all 16 segs (cheap, chip-wide parallel).
// ---------------------------------------------------------------------------
__global__ __launch_bounds__(256) void k12_fused(
    const float* __restrict__ xa, const float* __restrict__ xb,
    const float* __restrict__ ln_g, const float* __restrict__ ln_b,
    const float* __restrict__ wl, const float* __restrict__ bL,
    const float* __restrict__ wr, const float* __restrict__ bR,
    const float* __restrict__ w_out,
    __hip_bfloat16* __restrict__ a_bf, __hip_bfloat16* __restrict__ wb)
{
    const int bid  = blockIdx.x;
    const int t    = threadIdx.x;
    const int wv   = t >> 6;
    const int lane = t & 63;

    if (bid < NROW) {
        // ---------------- a-side: one row, 256 threads (r8 k1 verbatim) ----
        __shared__ float xn[D_SINGLE];
        __shared__ float red[8];
        const float* x = xa + bid * D_SINGLE;

        float x0 = x[t], x1 = x[t + 256];
        float s  = x0 + x1;
        float ss = x0 * x0 + x1 * x1;
        #pragma unroll
        for (int m = 1; m < 64; m <<= 1) {
            s  += __shfl_xor(s, m);
            ss += __shfl_xor(ss, m);
        }
        if (lane == 0) { red[wv] = s; red[4 + wv] = ss; }
        __syncthreads();
        float S    = red[0] + red[1] + red[2] + red[3];
        float SS   = red[4] + red[5] + red[6] + red[7];
        float mean = S * (1.0f / D_SINGLE);
        float var  = SS * (1.0f / D_SINGLE) - mean * mean;
        float rstd = rsqrtf(var + EPS);
        xn[t]       = (x0 - mean) * rstd * ln_g[t]       + ln_b[t];
        xn[t + 256] = (x1 - mean) * rstd * ln_g[t + 256] + ln_b[t + 256];
        __syncthreads();

        #pragma unroll
        for (int q = 0; q < 8; ++q) {
            const int r = wv + 4 * q;
            float acc = 0.f;
            #pragma unroll
            for (int tt = 0; tt < 8; ++tt) {
                const int k = lane + 64 * tt;
                acc += xn[k] * wl[r * D_SINGLE + k];
            }
            #pragma unroll
            for (int m = 1; m < 64; m <<= 1) acc += __shfl_xor(acc, m);
            if (lane == 0)
                a_bf[bid * RANK + r] = __float2bfloat16(acc + bL[r]);
        }
    } else {
        // ---------------- b-side ----------------
        const int bb  = bid - NROW;     // 0..1023
        const int g   = bb >> 4;        // j-group 0..63
        const int seg = bb & 15;        // pr sixteenth

        __shared__ __align__(16) float xnb[8][D_SINGLE];  // 16 KB
        __shared__ __align__(16) float bl[8 * RANK];      // 1 KB

        // B1: wave wv LNs rows wv and wv+4 of this j-group (2 rows/wave)
        #pragma unroll
        for (int rp = 0; rp < 2; ++rp) {
            const int jr = wv + 4 * rp;                   // 0..7
            const float* x = xb + (g * 8 + jr) * D_SINGLE;
            float v[8];
            float s = 0.f, ss = 0.f;
            #pragma unroll
            for (int k = 0; k < 8; ++k) {
                v[k] = x[lane + 64 * k];
                s += v[k]; ss += v[k] * v[k];
            }
            #pragma unroll
            for (int m = 1; m < 64; m <<= 1) {
                s  += __shfl_xor(s, m);
                ss += __shfl_xor(ss, m);
            }
            const float mean = s * (1.0f / D_SINGLE);
            const float var  = ss * (1.0f / D_SINGLE) - mean * mean;
            const float rstd = rsqrtf(var + EPS);
            #pragma unroll
            for (int k = 0; k < 8; ++k) {
                const int e = lane + 64 * k;
                xnb[jr][e] = (v[k] - mean) * rstd * ln_g[e] + ln_b[e];
            }
        }
        __syncthreads();

        // B2: thread t -> (jj, r): full dot-512 projection
        {
            const int jj = t >> 5;
            const int r  = t & 31;
            const f32x4* wr4 = reinterpret_cast<const f32x4*>(wr + r * D_SINGLE);
            const f32x4* xv4 = reinterpret_cast<const f32x4*>(&xnb[jj][0]);
            float acc = 0.f;
            #pragma unroll
            for (int k4 = 0; k4 < 128; ++k4)
                acc += dot4(wr4[k4], xv4[k4]);
            bl[jj * RANK + r] = acc + bR[r];
        }
        __syncthreads();

        // B3: thread t -> pr = seg*256 + t; 8 j-rows
        {
            const int pr = seg * 256 + t;
            const int p  = pr >> 5;
            const int rr = pr & 31;
            const f32x4* wrow = reinterpret_cast<const f32x4*>(w_out + p * (RANK * RANK) + rr * RANK);
            f32x4 w8[8];
            #pragma unroll
            for (int q = 0; q < 8; ++q) w8[q] = wrow[q];
            const f32x4* bl4 = reinterpret_cast<const f32x4*>(bl);
            #pragma unroll
            for (int jj = 0; jj < 8; ++jj) {
                float a2 = 0.f;
                #pragma unroll
                for (int q = 0; q < 8; ++q) a2 += dot4(w8[q], bl4[jj * 8 + q]);
                wb[(size_t)(g * 8 + jj) * 4096 + pr] = __float2bfloat16(a2);
            }
        }
    }
}

// ---------------------------------------------------------------------------
// Kernel 3 (byte-identical to round 8: MFMA + LDS-staged + nontemporal stores).
// C/D map: p = tt*16 + g*4 + r, i = i0 + c (m89-verified, passed r4-r9).
// ---------------------------------------------------------------------------
__global__ __launch_bounds__(256, 4) void k3_mfma(
    const __hip_bfloat16* __restrict__ a_bf, const __hip_bfloat16* __restrict__ wb_bf,
    const float* __restrict__ b_out, const float* __restrict__ lno_g,
    const float* __restrict__ lno_b, float* __restrict__ out)
{
    const int t    = threadIdx.x;
    const int wv   = t >> 6;          // 0..3 -> j within quad
    const int lane = t & 63;
    const int g    = lane >> 4;
    const int c    = lane & 15;
    const int jt   = blockIdx.x & 127;   // fast dim -> XCD j-locality
    const int ib   = blockIdx.x >> 7;    // 0..31
    const int j0   = jt * 4;
    const int i0   = ib * 16;
    const int j    = j0 + wv;

    __shared__ __align__(16) float L[16 * 4 * D_PAIR];   // 32 KB

    const short* a_s = reinterpret_cast<const short*>(a_bf);
    const short* wbj = reinterpret_cast<const short*>(wb_bf) + (size_t)j * 4096;

    // ---- Phase 1: MFMA + LN (all operand loads transient) ----
    bf16x8 bfrag = *reinterpret_cast<const bf16x8*>(a_s + (i0 + c) * RANK + g * 8);

    f32x4 acc[8];
    #pragma unroll
    for (int tt = 0; tt < 8; ++tt) {
        bf16x8 af  = *reinterpret_cast<const bf16x8*>(wbj + (tt * 16 + c) * RANK + g * 8);
        f32x4  cin = *reinterpret_cast<const f32x4*>(b_out + tt * 16 + g * 4);
        acc[tt] = __builtin_amdgcn_mfma_f32_16x16x32_bf16(af, bfrag, cin, 0, 0, 0);
    }

    float s = 0.f, ss = 0.f;
    #pragma unroll
    for (int tt = 0; tt < 8; ++tt) {
        #pragma unroll
        for (int r = 0; r < 4; ++r) { float v = acc[tt][r]; s += v; ss += v * v; }
    }
    s  += __shfl_xor(s, 16);  ss += __shfl_xor(ss, 16);
    s  += __shfl_xor(s, 32);  ss += __shfl_xor(ss, 32);
    const float mean = s * (1.0f / D_PAIR);
    const float var  = ss * (1.0f / D_PAIR) - mean * mean;
    const float rstd = rsqrtf(var + EPS);

    // normalized tile -> LDS, slot-swizzled (bits 4..6 ^= i&7)
    #pragma unroll
    for (int tt = 0; tt < 8; ++tt) {
        f32x4 gm = *reinterpret_cast<const f32x4*>(lno_g + tt * 16 + g * 4);
        f32x4 bt = *reinterpret_cast<const f32x4*>(lno_b + tt * 16 + g * 4);
        f32x4 o;
        #pragma unroll
        for (int r = 0; r < 4; ++r)
            o[r] = (acc[tt][r] - mean) * rstd * gm[r] + bt[r];
        int off = c * 2048 + wv * 512 + tt * 64 + g * 16;   // bytes
        off ^= (c & 7) << 4;
        *reinterpret_cast<f32x4*>(reinterpret_cast<char*>(L) + off) = o;
    }
    __syncthreads();

    // ---- Phase 2: coalesced nontemporal sweep store ----
    const int f     = t & 127;        // 128 threads cover one i-row (2 KB)
    const int ihalf = t >> 7;         // 2 rows per round
    #pragma unroll
    for (int rnd = 0; rnd < 8; ++rnd) {
        const int i = rnd * 2 + ihalf;
        int off = i * 2048 + f * 16;
        off ^= (i & 7) << 4;
        f32x4 v = *reinterpret_cast<const f32x4*>(reinterpret_cast<const char*>(L) + off);
        float* dst = out + (size_t)(i0 + i) * (NROW * D_PAIR) + j0 * D_PAIR + f * 4;
        __builtin_nontemporal_store(v, reinterpret_cast<f32x4*>(dst));
    }
}

// ---------------------------------------------------------------------------
extern "C" void kernel_launch(void* const* d_in, const int* in_sizes, int n_in,
                              void* d_out, int out_size, void* d_ws, size_t ws_size,
                              hipStream_t stream) {
    const float* single_a = (const float*)d_in[0];
    const float* single_b = (const float*)d_in[1];
    const float* ln_g     = (const float*)d_in[2];
    const float* ln_b     = (const float*)d_in[3];
    const float* w_left   = (const float*)d_in[4];
    const float* b_left   = (const float*)d_in[5];
    const float* w_right  = (const float*)d_in[6];
    const float* b_right  = (const float*)d_in[7];
    const float* w_out    = (const float*)d_in[8];
    const float* b_out    = (const float*)d_in[9];
    const float* lno_g    = (const float*)d_in[10];
    const float* lno_b    = (const float*)d_in[11];
    float* out = (float*)d_out;

    float* ws = (float*)d_ws;
    __hip_bfloat16* a_bf  = (__hip_bfloat16*)ws;                     // 512*32 bf16 = 32 KB
    __hip_bfloat16* wb_bf = (__hip_bfloat16*)(ws + 32768);           // 512*4096 bf16 = 4 MB

    k12_fused<<<NROW + 1024, 256, 0, stream>>>(single_a, single_b, ln_g, ln_b,
                                               w_left, b_left, w_right, b_right,
                                               w_out, a_bf, wb_bf);
    k3_mfma<<<4096, 256, 0, stream>>>(a_bf, wb_bf, b_out, lno_g, lno_b, out);
}

// Round 11
// 48.276 us; speedup vs baseline: 2.0332x; 2.0332x over previous
//
#include <hip/hip_runtime.h>
#include <hip/hip_bf16.h>
#include <math.h>

#define D_SINGLE 512
#define D_PAIR   128
#define RANK     32
#define NROW     512
#define EPS      1e-5f

typedef __attribute__((ext_vector_type(8))) short bf16x8;  // 8 bf16 = 4 VGPRs
typedef __attribute__((ext_vector_type(4))) float f32x4;

// ---------------------------------------------------------------------------
// Kernel 1 (r8 winner, verbatim): per-row LayerNorm + low-rank projection.
// ---------------------------------------------------------------------------
__global__ __launch_bounds__(256) void k1_ln_proj(
    const float* __restrict__ xa, const float* __restrict__ xb,
    const float* __restrict__ ln_g, const float* __restrict__ ln_b,
    const float* __restrict__ wl, const float* __restrict__ bl,
    const float* __restrict__ wr, const float* __restrict__ br,
    __hip_bfloat16* __restrict__ a_bf, float* __restrict__ b_proj)
{
    const int bid  = blockIdx.x;
    const int row  = bid & (NROW - 1);
    const bool isb = bid >= NROW;
    const float* x    = (isb ? xb : xa) + row * D_SINGLE;
    const float* W    = isb ? wr : wl;
    const float* bias = isb ? br : bl;
    float*           outf = b_proj + row * RANK;
    __hip_bfloat16*  outh = a_bf   + row * RANK;

    __shared__ float xn[D_SINGLE];
    __shared__ float red[8];

    const int t    = threadIdx.x;
    const int wave = t >> 6;
    const int lane = t & 63;

    float x0 = x[t], x1 = x[t + 256];
    float s  = x0 + x1;
    float ss = x0 * x0 + x1 * x1;
    #pragma unroll
    for (int m = 1; m < 64; m <<= 1) {
        s  += __shfl_xor(s, m);
        ss += __shfl_xor(ss, m);
    }
    if (lane == 0) { red[wave] = s; red[4 + wave] = ss; }
    __syncthreads();
    float S    = red[0] + red[1] + red[2] + red[3];
    float SS   = red[4] + red[5] + red[6] + red[7];
    float mean = S * (1.0f / D_SINGLE);
    float var  = SS * (1.0f / D_SINGLE) - mean * mean;
    float rstd = rsqrtf(var + EPS);
    xn[t]       = (x0 - mean) * rstd * ln_g[t]       + ln_b[t];
    xn[t + 256] = (x1 - mean) * rstd * ln_g[t + 256] + ln_b[t + 256];
    __syncthreads();

    #pragma unroll
    for (int q = 0; q < 8; ++q) {
        int r = wave + 4 * q;
        float acc = 0.f;
        #pragma unroll
        for (int tt = 0; tt < 8; ++tt) {
            int k = lane + 64 * tt;
            acc += xn[k] * W[r * D_SINGLE + k];
        }
        #pragma unroll
        for (int m = 1; m < 64; m <<= 1) acc += __shfl_xor(acc, m);
        if (lane == 0) {
            float v = acc + bias[r];
            if (isb) outf[r] = v;
            else     outh[r] = __float2bfloat16(v);
        }
    }
}

// ---------------------------------------------------------------------------
// Kernel 2 (r8 winner, verbatim): wb[j][p*32+r] = sum_s b[j][s]*w_out[p][r*32+s]
// ---------------------------------------------------------------------------
__global__ __launch_bounds__(256) void k2_wb(
    const float* __restrict__ bproj, const float* __restrict__ w_out,
    __hip_bfloat16* __restrict__ wb)
{
    const int g = blockIdx.x >> 4;   // j-group (8 rows of b)
    const int c = blockIdx.x & 15;   // pr chunk
    const int t = threadIdx.x;

    __shared__ float bl[8 * RANK];
    bl[t] = bproj[g * 8 * RANK + t];
    __syncthreads();

    const int pr = c * 256 + t;
    const int p  = pr >> 5;
    const int r  = pr & 31;

    const float4* wrow = reinterpret_cast<const float4*>(w_out + p * (RANK * RANK) + r * RANK);
    float4 w[8];
    #pragma unroll
    for (int q = 0; q < 8; ++q) w[q] = wrow[q];

    #pragma unroll
    for (int jj = 0; jj < 8; ++jj) {
        float acc = 0.f;
        #pragma unroll
        for (int q = 0; q < 8; ++q) {
            acc += bl[jj * 32 + 4 * q + 0] * w[q].x
                 + bl[jj * 32 + 4 * q + 1] * w[q].y
                 + bl[jj * 32 + 4 * q + 2] * w[q].z
                 + bl[jj * 32 + 4 * q + 3] * w[q].w;
        }
        wb[(size_t)(g * 8 + jj) * 4096 + pr] = __float2bfloat16(acc);
    }
}

// ---------------------------------------------------------------------------
// Kernel 3: r8 structure with the tile widened 16i x 8j (512 thr, 8 waves,
// one j per wave -- per-wave phase-1 code identical to r8). Phase-2 NT sweep
// now writes 4 KB contiguous per i-row (vs 2 KB in r8): halves HBM burst
// discontinuity. LDS 64 KB -> 2 blocks/CU x 8 waves = 4 waves/SIMD (same
// occupancy as r8). jt fast dim -> per-XCD 512 KB wb slice stays L2-resident.
// C/D map: p = tt*16 + g*4 + r, i = i0 + c (m89-verified, passed r4-r10).
// ---------------------------------------------------------------------------
__global__ __launch_bounds__(512, 4) void k3_mfma(
    const __hip_bfloat16* __restrict__ a_bf, const __hip_bfloat16* __restrict__ wb_bf,
    const float* __restrict__ b_out, const float* __restrict__ lno_g,
    const float* __restrict__ lno_b, float* __restrict__ out)
{
    const int t    = threadIdx.x;
    const int wv   = t >> 6;          // 0..7 -> j within octet
    const int lane = t & 63;
    const int g    = lane >> 4;
    const int c    = lane & 15;
    const int jt   = blockIdx.x & 63;    // fast dim -> XCD j-locality
    const int ib   = blockIdx.x >> 6;    // 0..31
    const int j0   = jt * 8;
    const int i0   = ib * 16;
    const int j    = j0 + wv;

    __shared__ __align__(16) float L[16 * 8 * D_PAIR];   // 64 KB

    const short* a_s = reinterpret_cast<const short*>(a_bf);
    const short* wbj = reinterpret_cast<const short*>(wb_bf) + (size_t)j * 4096;

    // ---- Phase 1 (per-wave, r8-identical): MFMA + LN, transient loads ----
    bf16x8 bfrag = *reinterpret_cast<const bf16x8*>(a_s + (i0 + c) * RANK + g * 8);

    f32x4 acc[8];
    #pragma unroll
    for (int tt = 0; tt < 8; ++tt) {
        bf16x8 af  = *reinterpret_cast<const bf16x8*>(wbj + (tt * 16 + c) * RANK + g * 8);
        f32x4  cin = *reinterpret_cast<const f32x4*>(b_out + tt * 16 + g * 4);
        acc[tt] = __builtin_amdgcn_mfma_f32_16x16x32_bf16(af, bfrag, cin, 0, 0, 0);
    }

    float s = 0.f, ss = 0.f;
    #pragma unroll
    for (int tt = 0; tt < 8; ++tt) {
        #pragma unroll
        for (int r = 0; r < 4; ++r) { float v = acc[tt][r]; s += v; ss += v * v; }
    }
    s  += __shfl_xor(s, 16);  ss += __shfl_xor(ss, 16);
    s  += __shfl_xor(s, 32);  ss += __shfl_xor(ss, 32);
    const float mean = s * (1.0f / D_PAIR);
    const float var  = ss * (1.0f / D_PAIR) - mean * mean;
    const float rstd = rsqrtf(var + EPS);

    // normalized tile -> LDS [i:4KB][j:512B][p-slot], bits 4..6 ^= i&7
    #pragma unroll
    for (int tt = 0; tt < 8; ++tt) {
        f32x4 gm = *reinterpret_cast<const f32x4*>(lno_g + tt * 16 + g * 4);
        f32x4 bt = *reinterpret_cast<const f32x4*>(lno_b + tt * 16 + g * 4);
        f32x4 o;
        #pragma unroll
        for (int r = 0; r < 4; ++r)
            o[r] = (acc[tt][r] - mean) * rstd * gm[r] + bt[r];
        int off = c * 4096 + wv * 512 + tt * 64 + g * 16;   // bytes
        off ^= (c & 7) << 4;
        *reinterpret_cast<f32x4*>(reinterpret_cast<char*>(L) + off) = o;
    }
    __syncthreads();

    // ---- Phase 2: nontemporal sweep, 4 KB contiguous per i-row ----
    const int f     = t & 255;        // 256 threads cover one i-row (4 KB)
    const int ihalf = t >> 8;         // 2 rows per round
    #pragma unroll
    for (int rnd = 0; rnd < 8; ++rnd) {
        const int i = rnd * 2 + ihalf;
        int off = i * 4096 + f * 16;
        off ^= (i & 7) << 4;
        f32x4 v = *reinterpret_cast<const f32x4*>(reinterpret_cast<const char*>(L) + off);
        float* dst = out + (size_t)(i0 + i) * (NROW * D_PAIR) + j0 * D_PAIR + f * 4;
        __builtin_nontemporal_store(v, reinterpret_cast<f32x4*>(dst));
    }
}

// ---------------------------------------------------------------------------
extern "C" void kernel_launch(void* const* d_in, const int* in_sizes, int n_in,
                              void* d_out, int out_size, void* d_ws, size_t ws_size,
                              hipStream_t stream) {
    const float* single_a = (const float*)d_in[0];
    const float* single_b = (const float*)d_in[1];
    const float* ln_g     = (const float*)d_in[2];
    const float* ln_b     = (const float*)d_in[3];
    const float* w_left   = (const float*)d_in[4];
    const float* b_left   = (const float*)d_in[5];
    const float* w_right  = (const float*)d_in[6];
    const float* b_right  = (const float*)d_in[7];
    const float* w_out    = (const float*)d_in[8];
    const float* b_out    = (const float*)d_in[9];
    const float* lno_g    = (const float*)d_in[10];
    const float* lno_b    = (const float*)d_in[11];
    float* out = (float*)d_out;

    float* ws = (float*)d_ws;
    __hip_bfloat16* a_bf   = (__hip_bfloat16*)ws;                    // 512*32 bf16 = 32 KB
    float*          b_proj = ws + 16384;                             // 512*32 f32
    __hip_bfloat16* wb_bf  = (__hip_bfloat16*)(ws + 32768);          // 512*4096 bf16 = 4 MB

    k1_ln_proj<<<2 * NROW, 256, 0, stream>>>(single_a, single_b, ln_g, ln_b,
                                             w_left, b_left, w_right, b_right,
                                             a_bf, b_proj);
    k2_wb<<<1024, 256, 0, stream>>>(b_proj, w_out, wb_bf);
    k3_mfma<<<2048, 512, 0, stream>>>(a_bf, wb_bf, b_out, lno_g, lno_b, out);
}

// Round 12
// 46.848 us; speedup vs baseline: 2.0952x; 1.0305x over previous
//
#include <hip/hip_runtime.h>
#include <hip/hip_bf16.h>
#include <math.h>

#define D_SINGLE 512
#define D_PAIR   128
#define RANK     32
#define NROW     512
#define EPS      1e-5f

typedef __attribute__((ext_vector_type(8))) short bf16x8;  // 8 bf16 = 4 VGPRs
typedef __attribute__((ext_vector_type(4))) float f32x4;

// ---------------------------------------------------------------------------
// Kernel 1 (r8 winner, verbatim): per-row LayerNorm + low-rank projection.
// ---------------------------------------------------------------------------
__global__ __launch_bounds__(256) void k1_ln_proj(
    const float* __restrict__ xa, const float* __restrict__ xb,
    const float* __restrict__ ln_g, const float* __restrict__ ln_b,
    const float* __restrict__ wl, const float* __restrict__ bl,
    const float* __restrict__ wr, const float* __restrict__ br,
    __hip_bfloat16* __restrict__ a_bf, float* __restrict__ b_proj)
{
    const int bid  = blockIdx.x;
    const int row  = bid & (NROW - 1);
    const bool isb = bid >= NROW;
    const float* x    = (isb ? xb : xa) + row * D_SINGLE;
    const float* W    = isb ? wr : wl;
    const float* bias = isb ? br : bl;
    float*           outf = b_proj + row * RANK;
    __hip_bfloat16*  outh = a_bf   + row * RANK;

    __shared__ float xn[D_SINGLE];
    __shared__ float red[8];

    const int t    = threadIdx.x;
    const int wave = t >> 6;
    const int lane = t & 63;

    float x0 = x[t], x1 = x[t + 256];
    float s  = x0 + x1;
    float ss = x0 * x0 + x1 * x1;
    #pragma unroll
    for (int m = 1; m < 64; m <<= 1) {
        s  += __shfl_xor(s, m);
        ss += __shfl_xor(ss, m);
    }
    if (lane == 0) { red[wave] = s; red[4 + wave] = ss; }
    __syncthreads();
    float S    = red[0] + red[1] + red[2] + red[3];
    float SS   = red[4] + red[5] + red[6] + red[7];
    float mean = S * (1.0f / D_SINGLE);
    float var  = SS * (1.0f / D_SINGLE) - mean * mean;
    float rstd = rsqrtf(var + EPS);
    xn[t]       = (x0 - mean) * rstd * ln_g[t]       + ln_b[t];
    xn[t + 256] = (x1 - mean) * rstd * ln_g[t + 256] + ln_b[t + 256];
    __syncthreads();

    #pragma unroll
    for (int q = 0; q < 8; ++q) {
        int r = wave + 4 * q;
        float acc = 0.f;
        #pragma unroll
        for (int tt = 0; tt < 8; ++tt) {
            int k = lane + 64 * tt;
            acc += xn[k] * W[r * D_SINGLE + k];
        }
        #pragma unroll
        for (int m = 1; m < 64; m <<= 1) acc += __shfl_xor(acc, m);
        if (lane == 0) {
            float v = acc + bias[r];
            if (isb) outf[r] = v;
            else     outh[r] = __float2bfloat16(v);
        }
    }
}

// ---------------------------------------------------------------------------
// Kernel 2 (r8 winner, verbatim): wb[j][p*32+r] = sum_s b[j][s]*w_out[p][r*32+s]
// ---------------------------------------------------------------------------
__global__ __launch_bounds__(256) void k2_wb(
    const float* __restrict__ bproj, const float* __restrict__ w_out,
    __hip_bfloat16* __restrict__ wb)
{
    const int g = blockIdx.x >> 4;   // j-group (8 rows of b)
    const int c = blockIdx.x & 15;   // pr chunk
    const int t = threadIdx.x;

    __shared__ float bl[8 * RANK];
    bl[t] = bproj[g * 8 * RANK + t];
    __syncthreads();

    const int pr = c * 256 + t;
    const int p  = pr >> 5;
    const int r  = pr & 31;

    const float4* wrow = reinterpret_cast<const float4*>(w_out + p * (RANK * RANK) + r * RANK);
    float4 w[8];
    #pragma unroll
    for (int q = 0; q < 8; ++q) w[q] = wrow[q];

    #pragma unroll
    for (int jj = 0; jj < 8; ++jj) {
        float acc = 0.f;
        #pragma unroll
        for (int q = 0; q < 8; ++q) {
            acc += bl[jj * 32 + 4 * q + 0] * w[q].x
                 + bl[jj * 32 + 4 * q + 1] * w[q].y
                 + bl[jj * 32 + 4 * q + 2] * w[q].z
                 + bl[jj * 32 + 4 * q + 3] * w[q].w;
        }
        wb[(size_t)(g * 8 + jj) * 4096 + pr] = __float2bfloat16(acc);
    }
}

// ---------------------------------------------------------------------------
// Kernel 3: r8 winner body, SINGLE CHANGE: __launch_bounds__(256, 5).
// LDS 32 KB permits 5 blocks/CU; min-waves 5 caps VGPR at ~102 (live set
// ~60-70, no spill expected) -> resident waves 16 -> 20 per CU (+25%
// phase-overlap depth between independent blocks).
// C/D map: p = tt*16 + g*4 + r, i = i0 + c (m89-verified, passed r4-r11).
// ---------------------------------------------------------------------------
__global__ __launch_bounds__(256, 5) void k3_mfma(
    const __hip_bfloat16* __restrict__ a_bf, const __hip_bfloat16* __restrict__ wb_bf,
    const float* __restrict__ b_out, const float* __restrict__ lno_g,
    const float* __restrict__ lno_b, float* __restrict__ out)
{
    const int t    = threadIdx.x;
    const int wv   = t >> 6;          // 0..3 -> j within quad
    const int lane = t & 63;
    const int g    = lane >> 4;
    const int c    = lane & 15;
    const int jt   = blockIdx.x & 127;   // fast dim -> XCD j-locality
    const int ib   = blockIdx.x >> 7;    // 0..31
    const int j0   = jt * 4;
    const int i0   = ib * 16;
    const int j    = j0 + wv;

    __shared__ __align__(16) float L[16 * 4 * D_PAIR];   // 32 KB

    const short* a_s = reinterpret_cast<const short*>(a_bf);
    const short* wbj = reinterpret_cast<const short*>(wb_bf) + (size_t)j * 4096;

    // ---- Phase 1: MFMA + LN (all operand loads transient) ----
    bf16x8 bfrag = *reinterpret_cast<const bf16x8*>(a_s + (i0 + c) * RANK + g * 8);

    f32x4 acc[8];
    #pragma unroll
    for (int tt = 0; tt < 8; ++tt) {
        bf16x8 af  = *reinterpret_cast<const bf16x8*>(wbj + (tt * 16 + c) * RANK + g * 8);
        f32x4  cin = *reinterpret_cast<const f32x4*>(b_out + tt * 16 + g * 4);
        acc[tt] = __builtin_amdgcn_mfma_f32_16x16x32_bf16(af, bfrag, cin, 0, 0, 0);
    }

    float s = 0.f, ss = 0.f;
    #pragma unroll
    for (int tt = 0; tt < 8; ++tt) {
        #pragma unroll
        for (int r = 0; r < 4; ++r) { float v = acc[tt][r]; s += v; ss += v * v; }
    }
    s  += __shfl_xor(s, 16);  ss += __shfl_xor(ss, 16);
    s  += __shfl_xor(s, 32);  ss += __shfl_xor(ss, 32);
    const float mean = s * (1.0f / D_PAIR);
    const float var  = ss * (1.0f / D_PAIR) - mean * mean;
    const float rstd = rsqrtf(var + EPS);

    // normalized tile -> LDS, slot-swizzled (bits 4..6 ^= i&7)
    #pragma unroll
    for (int tt = 0; tt < 8; ++tt) {
        f32x4 gm = *reinterpret_cast<const f32x4*>(lno_g + tt * 16 + g * 4);
        f32x4 bt = *reinterpret_cast<const f32x4*>(lno_b + tt * 16 + g * 4);
        f32x4 o;
        #pragma unroll
        for (int r = 0; r < 4; ++r)
            o[r] = (acc[tt][r] - mean) * rstd * gm[r] + bt[r];
        int off = c * 2048 + wv * 512 + tt * 64 + g * 16;   // bytes
        off ^= (c & 7) << 4;
        *reinterpret_cast<f32x4*>(reinterpret_cast<char*>(L) + off) = o;
    }
    __syncthreads();

    // ---- Phase 2: coalesced nontemporal sweep store ----
    const int f     = t & 127;        // 128 threads cover one i-row (2 KB)
    const int ihalf = t >> 7;         // 2 rows per round
    #pragma unroll
    for (int rnd = 0; rnd < 8; ++rnd) {
        const int i = rnd * 2 + ihalf;
        int off = i * 2048 + f * 16;
        off ^= (i & 7) << 4;
        f32x4 v = *reinterpret_cast<const f32x4*>(reinterpret_cast<const char*>(L) + off);
        float* dst = out + (size_t)(i0 + i) * (NROW * D_PAIR) + j0 * D_PAIR + f * 4;
        __builtin_nontemporal_store(v, reinterpret_cast<f32x4*>(dst));
    }
}

// ---------------------------------------------------------------------------
extern "C" void kernel_launch(void* const* d_in, const int* in_sizes, int n_in,
                              void* d_out, int out_size, void* d_ws, size_t ws_size,
                              hipStream_t stream) {
    const float* single_a = (const float*)d_in[0];
    const float* single_b = (const float*)d_in[1];
    const float* ln_g     = (const float*)d_in[2];
    const float* ln_b     = (const float*)d_in[3];
    const float* w_left   = (const float*)d_in[4];
    const float* b_left   = (const float*)d_in[5];
    const float* w_right  = (const float*)d_in[6];
    const float* b_right  = (const float*)d_in[7];
    const float* w_out    = (const float*)d_in[8];
    const float* b_out    = (const float*)d_in[9];
    const float* lno_g    = (const float*)d_in[10];
    const float* lno_b    = (const float*)d_in[11];
    float* out = (float*)d_out;

    float* ws = (float*)d_ws;
    __hip_bfloat16* a_bf   = (__hip_bfloat16*)ws;                    // 512*32 bf16 = 32 KB
    float*          b_proj = ws + 16384;                             // 512*32 f32
    __hip_bfloat16* wb_bf  = (__hip_bfloat16*)(ws + 32768);          // 512*4096 bf16 = 4 MB

    k1_ln_proj<<<2 * NROW, 256, 0, stream>>>(single_a, single_b, ln_g, ln_b,
                                             w_left, b_left, w_right, b_right,
                                             a_bf, b_proj);
    k2_wb<<<1024, 256, 0, stream>>>(b_proj, w_out, wb_bf);
    k3_mfma<<<4096, 256, 0, stream>>>(a_bf, wb_bf, b_out, lno_g, lno_b, out);
}